// Round 4
// baseline (1360.379 us; speedup 1.0000x reference)
//
#include <hip/hip_runtime.h>
#include <hip/hip_bf16.h>
#include <math.h>

// Shapes
#define N_TRAIN 4096
#define N_FEAT  64
#define N_HID   256
#define ENC     256
#define N_ANTES 2048
#define ATT_H   256
#define MAX_LEN 16

typedef unsigned int u32;

__device__ __forceinline__ float fsig(float x)  { return 1.f / (1.f + __expf(-x)); }
__device__ __forceinline__ float ftanh(float x) { return 2.f / (1.f + __expf(-2.f * x)) - 1.f; }

#if defined(__has_builtin)
#if __has_builtin(__builtin_amdgcn_global_load_lds)
#define HAS_GLLDS 1
#endif
#endif

// Async global->LDS, 16 B per lane. LDS dest = wave-uniform base + lane*16,
// which matches our contiguous per-lane layout (thread tid owns floats
// [4*tid, 4*tid+4) of each staged row).
__device__ __forceinline__ void gl2lds16(const float* g, float* l) {
#ifdef HAS_GLLDS
    __builtin_amdgcn_global_load_lds(
        (const __attribute__((address_space(1))) u32*)g,
        (__attribute__((address_space(3))) u32*)l, 16, 0, 0);
#else
    *(float4*)l = *(const float4*)g;   // sync fallback; barrier precedes use
#endif
}

// ---------------------------------------------------------------------------
// Tiled GEMM: C[m,n] = act(bias[n] + sum_k A[m,k] * B[n,k]); 64x64x16 tiles.
// Pad 68 floats keeps every float4 LDS read 16B-aligned -> ds_read_b128.
// ---------------------------------------------------------------------------
template <bool RELU>
__global__ __launch_bounds__(256) void gemm_abT(
    const float* __restrict__ A, const float* __restrict__ B,
    const float* __restrict__ bias, float* __restrict__ C,
    int M, int N, int K, int lda, int ldb, int ldc)
{
    __shared__ __align__(16) float As[16][68];
    __shared__ __align__(16) float Bs[16][68];
    const int tid = threadIdx.x;
    const int m0 = blockIdx.x * 64, n0 = blockIdx.y * 64;
    const int tx = tid & 15, ty = tid >> 4;
    const int kl = tid & 15, rl = tid >> 4;
    float acc[4][4] = {};

    for (int k0 = 0; k0 < K; k0 += 16) {
        #pragma unroll
        for (int pp = 0; pp < 4; ++pp) {
            int r = rl + pp * 16;
            As[kl][r] = A[(size_t)(m0 + r) * lda + k0 + kl];
            Bs[kl][r] = B[(size_t)(n0 + r) * ldb + k0 + kl];
        }
        __syncthreads();
        #pragma unroll
        for (int k = 0; k < 16; ++k) {
            float4 av = *(const float4*)&As[k][ty * 4];
            float4 bv = *(const float4*)&Bs[k][tx * 4];
            float a4[4] = {av.x, av.y, av.z, av.w};
            float b4[4] = {bv.x, bv.y, bv.z, bv.w};
            #pragma unroll
            for (int i = 0; i < 4; ++i)
                #pragma unroll
                for (int j = 0; j < 4; ++j)
                    acc[i][j] = fmaf(a4[i], b4[j], acc[i][j]);
        }
        __syncthreads();
    }
    #pragma unroll
    for (int i = 0; i < 4; ++i) {
        int m = m0 + ty * 4 + i;
        #pragma unroll
        for (int j = 0; j < 4; ++j) {
            int n = n0 + tx * 4 + j;
            float v = acc[i][j] + bias[n];
            if (RELU) v = fmaxf(v, 0.f);
            C[(size_t)m * ldc + n] = v;
        }
    }
}

// ---------------------------------------------------------------------------
// Split-K GEMM, partials to plain buffers (no atomics). Grid (M/64,N/64,4).
// z=0,1 -> pA slices, z=2,3 -> pB slices. Used for preT = Wa @ S.
// ---------------------------------------------------------------------------
#define KSPLIT 4
__global__ __launch_bounds__(256) void gemm_ab_splitk(
    const float* __restrict__ A, const float* __restrict__ B,
    float* __restrict__ pA, float* __restrict__ pB,
    int M, int N, int K, int lda, int ldb, int ldc)
{
    __shared__ __align__(16) float As[16][68];
    __shared__ __align__(16) float Bs[16][64];
    const int tid = threadIdx.x;
    const int m0 = blockIdx.x * 64, n0 = blockIdx.y * 64;
    const int kchunk = K / KSPLIT;
    const int kbeg = blockIdx.z * kchunk, kend = kbeg + kchunk;
    const int tx = tid & 15, ty = tid >> 4;
    const int kl = tid & 15, rl = tid >> 4;
    const int kb = tid >> 6, nb = tid & 63;
    float acc[4][4] = {};

    for (int k0 = kbeg; k0 < kend; k0 += 16) {
        #pragma unroll
        for (int pp = 0; pp < 4; ++pp) {
            As[kl][rl + pp * 16] = A[(size_t)(m0 + rl + pp * 16) * lda + k0 + kl];
            Bs[kb + pp * 4][nb]  = B[(size_t)(k0 + kb + pp * 4) * ldb + n0 + nb];
        }
        __syncthreads();
        #pragma unroll
        for (int k = 0; k < 16; ++k) {
            float4 av = *(const float4*)&As[k][ty * 4];
            float4 bv = *(const float4*)&Bs[k][tx * 4];
            float a4[4] = {av.x, av.y, av.z, av.w};
            float b4[4] = {bv.x, bv.y, bv.z, bv.w};
            #pragma unroll
            for (int i = 0; i < 4; ++i)
                #pragma unroll
                for (int j = 0; j < 4; ++j)
                    acc[i][j] = fmaf(a4[i], b4[j], acc[i][j]);
        }
        __syncthreads();
    }
    float* Cp = (blockIdx.z < 2) ? (pA + (size_t)blockIdx.z * (ATT_H * N_ANTES))
                                 : (pB + (size_t)(blockIdx.z - 2) * (ATT_H * N_ANTES));
    #pragma unroll
    for (int i = 0; i < 4; ++i)
        #pragma unroll
        for (int j = 0; j < 4; ++j)
            Cp[(size_t)(m0 + ty * 4 + i) * ldc + n0 + tx * 4 + j] = acc[i][j];
}

__global__ __launch_bounds__(256) void k_reduce(
    const float* __restrict__ pA, const float* __restrict__ pB,
    float* __restrict__ preT)
{
    int gid = blockIdx.x * 256 + threadIdx.x;   // 0..524287
    const int SZ = ATT_H * N_ANTES;
    preT[gid] = (pA[gid] + pA[gid + SZ]) + (pB[gid] + pB[gid + SZ]);
}

// ---------------------------------------------------------------------------
// rowsum[j] = sum_k w_ih[j, k]
// ---------------------------------------------------------------------------
__global__ __launch_bounds__(256) void k_rowsum(const float* __restrict__ w_ih,
                                                float* __restrict__ rowsum)
{
    __shared__ float red[256];
    const int j = blockIdx.x, tid = threadIdx.x;
    float s = 0.f;
    for (int i = tid; i < N_ANTES; i += 256) s += w_ih[(size_t)j * N_ANTES + i];
    red[tid] = s; __syncthreads();
    for (int off = 128; off > 0; off >>= 1) {
        if (tid < off) red[tid] += red[tid + off];
        __syncthreads();
    }
    if (tid == 0) rowsum[j] = red[0];
}

// ---------------------------------------------------------------------------
// w_pack[k*1024 + jj*4 + g] = w_hh[(g*256+jj)*256 + k]
// ---------------------------------------------------------------------------
__global__ __launch_bounds__(256) void k_pack(const float* __restrict__ w_hh,
                                              float* __restrict__ w_pack)
{
    int gid = blockIdx.x * 256 + threadIdx.x;  // 0..262143
    int row = gid >> 8;
    int k   = gid & 255;
    int g   = row >> 8, jj = row & 255;
    w_pack[(size_t)k * 1024 + jj * 4 + g] = w_hh[gid];
}

// ---------------------------------------------------------------------------
// WbT[k*256 + j] = att_w1[j*(N_TRAIN+ENC) + N_TRAIN + k]
// ---------------------------------------------------------------------------
__global__ __launch_bounds__(256) void k_wbT(const float* __restrict__ att_w1,
                                             float* __restrict__ WbT)
{
    int gid = blockIdx.x * 256 + threadIdx.x;  // 0..65535
    int j = gid >> 8, k = gid & 255;
    WbT[(size_t)k * 256 + j] = att_w1[(size_t)j * (N_TRAIN + ENC) + N_TRAIN + k];
}

// ---------------------------------------------------------------------------
// LSTM step. 16 rows/block, thread tid = hidden unit jj, all 4 gates.
// w_pack (1 MB, L2-resident) streamed via double-buffered async global->LDS
// DMA in 4-row (16 KB) chunks; DMA for chunk i+1 issued before computing
// chunk i (512 cyc of FMA cover ~250 cyc L2 latency), __syncthreads drains.
// h tile in LDS as [k][r] (64 B rows) -> broadcast ds_read_b128.
// ---------------------------------------------------------------------------
#define ROWS 16
#define CH 4
#define NCH 64
__global__ __launch_bounds__(256) void k_lstm(
    float* __restrict__ h, float* __restrict__ c,
    const float* __restrict__ w_pack, const float* __restrict__ rowsum,
    const float* __restrict__ b_ih, const float* __restrict__ b_hh,
    const float* __restrict__ S, const int* __restrict__ idx_buf, int t,
    float* __restrict__ e_accum_t)
{
    __shared__ __align__(16) float h_lds[256 * ROWS];      // [k][r], 16 KB
    __shared__ __align__(16) float w_lds[2][CH * 1024];    // 2 x 16 KB
    __shared__ float a_lds[ROWS];
    const int tid = threadIdx.x;
    const int n0 = blockIdx.x * ROWS;

    if (tid < ROWS) {
        float a = 1.0f;
        if (t > 0) a = S[(size_t)(n0 + tid) * N_ANTES + idx_buf[t - 1]];
        a_lds[tid] = a;
    }
    // stage h tile -> [k][r]
    float hreg[ROWS];
    #pragma unroll
    for (int r = 0; r < ROWS; ++r) hreg[r] = h[(size_t)(n0 + r) * 256 + tid];
    #pragma unroll
    for (int q = 0; q < 4; ++q)
        *(float4*)&h_lds[tid * ROWS + q * 4] =
            make_float4(hreg[q*4], hreg[q*4+1], hreg[q*4+2], hreg[q*4+3]);

    // prefetch chunk 0
    #pragma unroll
    for (int kk = 0; kk < CH; ++kk)
        gl2lds16(w_pack + (size_t)kk * 1024 + tid * 4,
                 &w_lds[0][kk * 1024 + tid * 4]);

    float rs[4], bs[4];
    #pragma unroll
    for (int g = 0; g < 4; ++g) {
        int j = g * 256 + tid;
        rs[g] = rowsum[j];
        bs[g] = b_ih[j] + b_hh[j];
    }

    __syncthreads();   // drains chunk-0 DMA + h_lds/a_lds writes

    float acc[4][ROWS];
    #pragma unroll
    for (int g = 0; g < 4; ++g)
        #pragma unroll
        for (int r = 0; r < ROWS; ++r)
            acc[g][r] = fmaf(a_lds[r], rs[g], bs[g]);

    for (int ch = 0; ch < NCH; ++ch) {
        if (ch + 1 < NCH) {
            const float* src = w_pack + (size_t)(ch + 1) * CH * 1024;
            float* dst = w_lds[(ch + 1) & 1];
            #pragma unroll
            for (int kk = 0; kk < CH; ++kk)
                gl2lds16(src + kk * 1024 + tid * 4, dst + kk * 1024 + tid * 4);
        }
        const float* wb = w_lds[ch & 1];
        #pragma unroll
        for (int kk = 0; kk < CH; ++kk) {
            const int k = ch * CH + kk;
            float4 w = *(const float4*)&wb[kk * 1024 + tid * 4];
            const float4* hrow = (const float4*)&h_lds[k * ROWS];
            float4 h0 = hrow[0], h1 = hrow[1], h2 = hrow[2], h3 = hrow[3];
            float hk[ROWS] = {h0.x, h0.y, h0.z, h0.w, h1.x, h1.y, h1.z, h1.w,
                              h2.x, h2.y, h2.z, h2.w, h3.x, h3.y, h3.z, h3.w};
            #pragma unroll
            for (int r = 0; r < ROWS; ++r) {
                acc[0][r] = fmaf(w.x, hk[r], acc[0][r]);
                acc[1][r] = fmaf(w.y, hk[r], acc[1][r]);
                acc[2][r] = fmaf(w.z, hk[r], acc[2][r]);
                acc[3][r] = fmaf(w.w, hk[r], acc[3][r]);
            }
        }
        __syncthreads();   // waits compute readers + the (old) in-flight DMA
    }

    float esum = 0.f;
    #pragma unroll
    for (int r = 0; r < ROWS; ++r) {
        size_t off = (size_t)(n0 + r) * 256 + tid;
        float cold = c[off];
        float ig = fsig(acc[0][r]);
        float fg = fsig(acc[1][r]);
        float gg = ftanh(acc[2][r]);
        float og = fsig(acc[3][r]);
        float cn = fg * cold + ig * gg;
        float hn = og * ftanh(cn);
        c[off] = cn;
        h[off] = hn;
        esum += hn;
    }
    atomicAdd(&e_accum_t[tid], esum);
}

// ---------------------------------------------------------------------------
// Fused attention: 32 blocks compute 64 scores each; the last block to finish
// (device-scope counter) does log-softmax + argmax and writes out_t / idx_t.
// ---------------------------------------------------------------------------
__global__ __launch_bounds__(256) void k_att(
    const float* __restrict__ preT, const float* __restrict__ e_accum_t,
    const float* __restrict__ WbT, const float* __restrict__ att_b1,
    const float* __restrict__ att_w2, const float* __restrict__ att_b2,
    float* __restrict__ scores, float* __restrict__ out_t,
    int* __restrict__ idx_t, u32* __restrict__ counter)
{
    __shared__ float e_lds[256];
    __shared__ float u[256];
    __shared__ float w2s[256];
    __shared__ float red[256];
    __shared__ int   ridx[256];
    __shared__ u32 done;
    const int tid = threadIdx.x;

    e_lds[tid] = e_accum_t[tid] * (1.f / (float)N_TRAIN);
    w2s[tid] = att_w2[tid];
    __syncthreads();

    float uacc = att_b1[tid];
    for (int k = 0; k < 256; ++k)
        uacc = fmaf(e_lds[k], WbT[(size_t)k * 256 + tid], uacc);
    u[tid] = uacc;
    __syncthreads();

    const int pl = tid & 63, jq = tid >> 6;
    const int p = blockIdx.x * 64 + pl;
    float sc = 0.f;
    #pragma unroll 4
    for (int j = jq; j < 256; j += 4) {
        float v = preT[(size_t)j * N_ANTES + p] + u[j];
        sc = fmaf(fmaxf(v, 0.f), w2s[j], sc);
    }
    red[tid] = sc;
    __syncthreads();
    if (tid < 64) {
        float s = red[tid] + red[tid + 64] + red[tid + 128] + red[tid + 192]
                + att_b2[0];
        __hip_atomic_store(&scores[blockIdx.x * 64 + tid], s,
                           __ATOMIC_RELAXED, __HIP_MEMORY_SCOPE_AGENT);
    }
    __threadfence();
    __syncthreads();
    if (tid == 0) done = atomicAdd(counter, 1u);
    __syncthreads();
    if (done != 31) return;
    __threadfence();

    // ---- last block: log-softmax + argmax over all 2048 scores ----
    float sv[8];
    #pragma unroll
    for (int i = 0; i < 8; ++i)
        sv[i] = __hip_atomic_load(&scores[tid * 8 + i],
                                  __ATOMIC_RELAXED, __HIP_MEMORY_SCOPE_AGENT);
    float lmax = -INFINITY; int lidx = 0;
    #pragma unroll
    for (int i = 0; i < 8; ++i)
        if (sv[i] > lmax) { lmax = sv[i]; lidx = tid * 8 + i; }
    red[tid] = lmax; ridx[tid] = lidx;
    __syncthreads();
    for (int off = 128; off > 0; off >>= 1) {
        if (tid < off) {
            float ov = red[tid + off]; int oi = ridx[tid + off];
            if (ov > red[tid] || (ov == red[tid] && oi < ridx[tid])) {
                red[tid] = ov; ridx[tid] = oi;
            }
        }
        __syncthreads();
    }
    const float gmax = red[0];
    const int gidx = ridx[0];
    __syncthreads();

    float lsum = 0.f;
    #pragma unroll
    for (int i = 0; i < 8; ++i) lsum += __expf(sv[i] - gmax);
    red[tid] = lsum;
    __syncthreads();
    for (int off = 128; off > 0; off >>= 1) {
        if (tid < off) red[tid] += red[tid + off];
        __syncthreads();
    }
    const float lse = gmax + logf(red[0]);

    #pragma unroll
    for (int i = 0; i < 8; ++i)
        out_t[tid * 8 + i] = sv[i] - lse;
    if (tid == 0) idx_t[0] = gidx;
}

// ---------------------------------------------------------------------------
extern "C" void kernel_launch(void* const* d_in, const int* in_sizes, int n_in,
                              void* d_out, int out_size, void* d_ws, size_t ws_size,
                              hipStream_t stream)
{
    (void)in_sizes; (void)n_in; (void)out_size; (void)ws_size;
    const float* context = (const float*)d_in[0];
    const float* S       = (const float*)d_in[1];
    const float* enc_w1  = (const float*)d_in[2];
    const float* enc_b1  = (const float*)d_in[3];
    const float* enc_w2  = (const float*)d_in[4];
    const float* enc_b2  = (const float*)d_in[5];
    const float* w_ih    = (const float*)d_in[6];
    const float* w_hh    = (const float*)d_in[7];
    const float* b_ih    = (const float*)d_in[8];
    const float* b_hh    = (const float*)d_in[9];
    const float* att_w1  = (const float*)d_in[10];
    const float* att_b1  = (const float*)d_in[11];
    const float* att_w2  = (const float*)d_in[12];
    const float* att_b2  = (const float*)d_in[13];
    float* out = (float*)d_out;
    float* ws  = (float*)d_ws;

    // ws layout (float offsets)
    float* h      = ws;                        // 1,048,576
    float* c      = ws + 1048576;              // 1,048,576
    float* buf4M  = ws + 2097152;              // hid1, then splitk partials z0,z1
    float* preT   = ws + 3145728;              // 524,288
    float* partB  = ws + 3670016;              // splitk partials z2,z3 (1,048,576)
    float* wpk    = ws + 4718592;              // 262,144
    float* rowsum = ws + 4980736;              // 1,024
    float* e_acc  = ws + 4981760;              // 4,096
    u32*   cnt    = (u32*)(ws + 4985856);      // 16
    float* scores = ws + 4985872;              // 2,048
    float* WbT    = ws + 4987920;              // 65,536
    int*   idxbuf = (int*)(ws + 5053456);      // 16

    hipMemsetAsync(c, 0, (size_t)N_TRAIN * ENC * sizeof(float), stream);
    // e_acc (16x256 floats) + 16 counters, contiguous
    hipMemsetAsync(e_acc, 0, (size_t)MAX_LEN * ENC * sizeof(float) + 16 * sizeof(u32), stream);

    k_rowsum<<<1024, 256, 0, stream>>>(w_ih, rowsum);
    k_pack<<<1024, 256, 0, stream>>>(w_hh, wpk);
    k_wbT<<<256, 256, 0, stream>>>(att_w1, WbT);

    // encoder: hid1 = relu(context @ enc_w1.T + b1); h = hid1 @ enc_w2.T + b2
    float* hid1 = buf4M;
    dim3 g1(N_TRAIN / 64, N_HID / 64);
    gemm_abT<true><<<g1, 256, 0, stream>>>(context, enc_w1, enc_b1, hid1,
                                           N_TRAIN, N_HID, N_FEAT, N_FEAT, N_FEAT, N_HID);
    dim3 g2(N_TRAIN / 64, ENC / 64);
    gemm_abT<false><<<g2, 256, 0, stream>>>(hid1, enc_w2, enc_b2, h,
                                            N_TRAIN, ENC, N_HID, N_HID, N_HID, ENC);
    // preT = Wa @ S via split-K partials (buf4M reused after gemm #2 read it)
    dim3 g3(ATT_H / 64, N_ANTES / 64, KSPLIT);
    gemm_ab_splitk<<<g3, 256, 0, stream>>>(att_w1, S, buf4M, partB,
                                           ATT_H, N_ANTES, N_TRAIN,
                                           N_TRAIN + ENC, N_ANTES, N_ANTES);
    k_reduce<<<(ATT_H * N_ANTES) / 256, 256, 0, stream>>>(buf4M, partB, preT);

    for (int t = 0; t < MAX_LEN; ++t) {
        k_lstm<<<N_TRAIN / ROWS, 256, 0, stream>>>(h, c, wpk, rowsum, b_ih, b_hh,
                                                   S, idxbuf, t, e_acc + t * 256);
        k_att<<<N_ANTES / 64, 256, 0, stream>>>(preT, e_acc + t * 256, WbT,
                                                att_b1, att_w2, att_b2, scores,
                                                out + t * N_ANTES, idxbuf + t,
                                                cnt + t);
    }
}

// Round 5
// 1066.358 us; speedup vs baseline: 1.2757x; 1.2757x over previous
//
#include <hip/hip_runtime.h>
#include <hip/hip_bf16.h>
#include <math.h>

// Shapes
#define N_TRAIN 4096
#define N_FEAT  64
#define N_HID   256
#define ENC     256
#define N_ANTES 2048
#define ATT_H   256
#define MAX_LEN 16

typedef unsigned int u32;

__device__ __forceinline__ float fsig(float x)  { return 1.f / (1.f + __expf(-x)); }
__device__ __forceinline__ float ftanh(float x) { return 2.f / (1.f + __expf(-2.f * x)) - 1.f; }

// ---------------------------------------------------------------------------
// Tiled GEMM: C[m,n] = act(bias[n] + sum_k A[m,k] * B[n,k]); 64x64x16 tiles.
// ---------------------------------------------------------------------------
template <bool RELU>
__global__ __launch_bounds__(256) void gemm_abT(
    const float* __restrict__ A, const float* __restrict__ B,
    const float* __restrict__ bias, float* __restrict__ C,
    int M, int N, int K, int lda, int ldb, int ldc)
{
    __shared__ __align__(16) float As[16][68];
    __shared__ __align__(16) float Bs[16][68];
    const int tid = threadIdx.x;
    const int m0 = blockIdx.x * 64, n0 = blockIdx.y * 64;
    const int tx = tid & 15, ty = tid >> 4;
    const int kl = tid & 15, rl = tid >> 4;
    float acc[4][4] = {};

    for (int k0 = 0; k0 < K; k0 += 16) {
        #pragma unroll
        for (int pp = 0; pp < 4; ++pp) {
            int r = rl + pp * 16;
            As[kl][r] = A[(size_t)(m0 + r) * lda + k0 + kl];
            Bs[kl][r] = B[(size_t)(n0 + r) * ldb + k0 + kl];
        }
        __syncthreads();
        #pragma unroll
        for (int k = 0; k < 16; ++k) {
            float4 av = *(const float4*)&As[k][ty * 4];
            float4 bv = *(const float4*)&Bs[k][tx * 4];
            float a4[4] = {av.x, av.y, av.z, av.w};
            float b4[4] = {bv.x, bv.y, bv.z, bv.w};
            #pragma unroll
            for (int i = 0; i < 4; ++i)
                #pragma unroll
                for (int j = 0; j < 4; ++j)
                    acc[i][j] = fmaf(a4[i], b4[j], acc[i][j]);
        }
        __syncthreads();
    }
    #pragma unroll
    for (int i = 0; i < 4; ++i) {
        int m = m0 + ty * 4 + i;
        #pragma unroll
        for (int j = 0; j < 4; ++j) {
            int n = n0 + tx * 4 + j;
            float v = acc[i][j] + bias[n];
            if (RELU) v = fmaxf(v, 0.f);
            C[(size_t)m * ldc + n] = v;
        }
    }
}

// ---------------------------------------------------------------------------
// Split-K GEMM, partials to plain buffers (no atomics). Grid (M/64,N/64,4).
// ---------------------------------------------------------------------------
#define KSPLIT 4
__global__ __launch_bounds__(256) void gemm_ab_splitk(
    const float* __restrict__ A, const float* __restrict__ B,
    float* __restrict__ pA, float* __restrict__ pB,
    int M, int N, int K, int lda, int ldb, int ldc)
{
    __shared__ __align__(16) float As[16][68];
    __shared__ __align__(16) float Bs[16][64];
    const int tid = threadIdx.x;
    const int m0 = blockIdx.x * 64, n0 = blockIdx.y * 64;
    const int kchunk = K / KSPLIT;
    const int kbeg = blockIdx.z * kchunk, kend = kbeg + kchunk;
    const int tx = tid & 15, ty = tid >> 4;
    const int kl = tid & 15, rl = tid >> 4;
    const int kb = tid >> 6, nb = tid & 63;
    float acc[4][4] = {};

    for (int k0 = kbeg; k0 < kend; k0 += 16) {
        #pragma unroll
        for (int pp = 0; pp < 4; ++pp) {
            As[kl][rl + pp * 16] = A[(size_t)(m0 + rl + pp * 16) * lda + k0 + kl];
            Bs[kb + pp * 4][nb]  = B[(size_t)(k0 + kb + pp * 4) * ldb + n0 + nb];
        }
        __syncthreads();
        #pragma unroll
        for (int k = 0; k < 16; ++k) {
            float4 av = *(const float4*)&As[k][ty * 4];
            float4 bv = *(const float4*)&Bs[k][tx * 4];
            float a4[4] = {av.x, av.y, av.z, av.w};
            float b4[4] = {bv.x, bv.y, bv.z, bv.w};
            #pragma unroll
            for (int i = 0; i < 4; ++i)
                #pragma unroll
                for (int j = 0; j < 4; ++j)
                    acc[i][j] = fmaf(a4[i], b4[j], acc[i][j]);
        }
        __syncthreads();
    }
    float* Cp = (blockIdx.z < 2) ? (pA + (size_t)blockIdx.z * (ATT_H * N_ANTES))
                                 : (pB + (size_t)(blockIdx.z - 2) * (ATT_H * N_ANTES));
    #pragma unroll
    for (int i = 0; i < 4; ++i)
        #pragma unroll
        for (int j = 0; j < 4; ++j)
            Cp[(size_t)(m0 + ty * 4 + i) * ldc + n0 + tx * 4 + j] = acc[i][j];
}

__global__ __launch_bounds__(256) void k_reduce(
    const float* __restrict__ pA, const float* __restrict__ pB,
    float* __restrict__ preT)
{
    int gid = blockIdx.x * 256 + threadIdx.x;
    const int SZ = ATT_H * N_ANTES;
    preT[gid] = (pA[gid] + pA[gid + SZ]) + (pB[gid] + pB[gid + SZ]);
}

// ---------------------------------------------------------------------------
// rowsum[j] = sum_k w_ih[j, k]
// ---------------------------------------------------------------------------
__global__ __launch_bounds__(256) void k_rowsum(const float* __restrict__ w_ih,
                                                float* __restrict__ rowsum)
{
    __shared__ float red[256];
    const int j = blockIdx.x, tid = threadIdx.x;
    float s = 0.f;
    for (int i = tid; i < N_ANTES; i += 256) s += w_ih[(size_t)j * N_ANTES + i];
    red[tid] = s; __syncthreads();
    for (int off = 128; off > 0; off >>= 1) {
        if (tid < off) red[tid] += red[tid + off];
        __syncthreads();
    }
    if (tid == 0) rowsum[j] = red[0];
}

// ---------------------------------------------------------------------------
// wpkT[k*1024 + j] = w_hh[j*256 + k]   (k-major: coalesced per-k loads)
// ---------------------------------------------------------------------------
__global__ __launch_bounds__(256) void k_packT(const float* __restrict__ w_hh,
                                               float* __restrict__ wpkT)
{
    int gid = blockIdx.x * 256 + threadIdx.x;  // 0..262143
    int j = gid >> 8;
    int k = gid & 255;
    wpkT[(size_t)k * 1024 + j] = w_hh[gid];
}

// ---------------------------------------------------------------------------
// WbT[k*256 + j] = att_w1[j*(N_TRAIN+ENC) + N_TRAIN + k]
// ---------------------------------------------------------------------------
__global__ __launch_bounds__(256) void k_wbT(const float* __restrict__ att_w1,
                                             float* __restrict__ WbT)
{
    int gid = blockIdx.x * 256 + threadIdx.x;  // 0..65535
    int j = gid >> 8, k = gid & 255;
    WbT[(size_t)k * 256 + j] = att_w1[(size_t)j * (N_TRAIN + ENC) + N_TRAIN + k];
}

// ---------------------------------------------------------------------------
// LSTM step, restructured for occupancy: 1024 threads/block, grid 256
// (16 waves/CU = 4/SIMD). Thread tid owns gate-row j = tid (j = g*256+jj).
// Per k: 1 coalesced global load of wpkT[k][j] (4-deep register prefetch,
// NO barrier in the K-loop -> no vmcnt drain) + 4 broadcast ds_read_b128 of
// the h tile + 16 FMAs. Gate exchange via z_lds, fused c/h update.
// ---------------------------------------------------------------------------
#define LROWS 16
#define HSTR 20
__global__ __launch_bounds__(1024, 4) void k_lstm(
    float* __restrict__ h, float* __restrict__ c,
    const float* __restrict__ wpkT, const float* __restrict__ rowsum,
    const float* __restrict__ b_ih, const float* __restrict__ b_hh,
    const float* __restrict__ S, const int* __restrict__ idx_buf, int t,
    float* __restrict__ e_accum_t)
{
    __shared__ __align__(16) float h_lds[256 * HSTR];        // [k][r], 20 KB
    __shared__ float z_lds[LROWS * 1024];                    // [r][j], 64 KB
    __shared__ float red[1024];
    __shared__ float a_lds[LROWS];
    const int tid = threadIdx.x;                             // 0..1023
    const int n0 = blockIdx.x * LROWS;

    if (tid < LROWS) {
        float a = 1.0f;
        if (t > 0) a = S[(size_t)(n0 + tid) * N_ANTES + idx_buf[t - 1]];
        a_lds[tid] = a;
    }
    // stage h tile -> h_lds[k][r] (threads 0..255, col k = tid)
    if (tid < 256) {
        float hreg[LROWS];
        #pragma unroll
        for (int r = 0; r < LROWS; ++r)
            hreg[r] = h[(size_t)(n0 + r) * 256 + tid];
        #pragma unroll
        for (int q = 0; q < 4; ++q)
            *(float4*)&h_lds[tid * HSTR + q * 4] =
                make_float4(hreg[q*4], hreg[q*4+1], hreg[q*4+2], hreg[q*4+3]);
    }

    // 4-deep rotating register prefetch of wpkT (padded +4 k-rows)
    float wbuf[4];
    #pragma unroll
    for (int i = 0; i < 4; ++i) wbuf[i] = wpkT[(size_t)i * 1024 + tid];

    const float rs = rowsum[tid];
    const float bs = b_ih[tid] + b_hh[tid];

    __syncthreads();

    float acc[LROWS];
    #pragma unroll
    for (int r = 0; r < LROWS; ++r) acc[r] = fmaf(a_lds[r], rs, bs);

    for (int k4 = 0; k4 < 256; k4 += 4) {
        #pragma unroll
        for (int u = 0; u < 4; ++u) {
            float w = wbuf[u];
            wbuf[u] = wpkT[(size_t)(k4 + 4 + u) * 1024 + tid];  // pad rows ok
            const float4* hrow = (const float4*)&h_lds[(k4 + u) * HSTR];
            float4 h0 = hrow[0], h1 = hrow[1], h2 = hrow[2], h3 = hrow[3];
            float hk[LROWS] = {h0.x, h0.y, h0.z, h0.w, h1.x, h1.y, h1.z, h1.w,
                               h2.x, h2.y, h2.z, h2.w, h3.x, h3.y, h3.z, h3.w};
            #pragma unroll
            for (int r = 0; r < LROWS; ++r)
                acc[r] = fmaf(w, hk[r], acc[r]);
        }
    }

    // exchange gates: z_lds[r][j]
    #pragma unroll
    for (int r = 0; r < LROWS; ++r) z_lds[r * 1024 + tid] = acc[r];
    __syncthreads();

    // fused gate update: thread handles (rbase, jj), rows rbase*4..rbase*4+3
    const int jj = tid & 255, rbase = tid >> 8;
    float esum = 0.f;
    #pragma unroll
    for (int i = 0; i < 4; ++i) {
        int r = rbase * 4 + i;
        float zi = z_lds[r * 1024 + jj];
        float zf = z_lds[r * 1024 + 256 + jj];
        float zg = z_lds[r * 1024 + 512 + jj];
        float zo = z_lds[r * 1024 + 768 + jj];
        size_t off = (size_t)(n0 + r) * 256 + jj;
        float cn = fsig(zf) * c[off] + fsig(zi) * ftanh(zg);
        float hn = fsig(zo) * ftanh(cn);
        c[off] = cn;
        h[off] = hn;
        esum += hn;
    }
    red[tid] = esum;
    __syncthreads();
    if (tid < 256) {
        float e = (red[tid] + red[tid + 256]) + (red[tid + 512] + red[tid + 768]);
        atomicAdd(&e_accum_t[tid], e);
    }
}

// ---------------------------------------------------------------------------
// Attention scores: 64 blocks, 32 cols each, 8 threads per col.
// u[j] = att_b1[j] + sum_k e_t[k]*WbT[k,j]  (redundant per block, coalesced)
// scores[p] = att_b2 + sum_j relu(preT[j,p] + u[j]) * att_w2[j]
// ---------------------------------------------------------------------------
__global__ __launch_bounds__(256) void k_att1(
    const float* __restrict__ preT, const float* __restrict__ e_accum_t,
    const float* __restrict__ WbT, const float* __restrict__ att_b1,
    const float* __restrict__ att_w2, const float* __restrict__ att_b2,
    float* __restrict__ scores)
{
    __shared__ float e_lds[256];
    __shared__ float u[256];
    __shared__ float w2s[256];
    __shared__ float red[256];
    const int tid = threadIdx.x;
    e_lds[tid] = e_accum_t[tid] * (1.f / (float)N_TRAIN);
    w2s[tid] = att_w2[tid];
    __syncthreads();

    float uacc = att_b1[tid];
    for (int k = 0; k < 256; ++k)
        uacc = fmaf(e_lds[k], WbT[(size_t)k * 256 + tid], uacc);
    u[tid] = uacc;
    __syncthreads();

    const int pl = tid & 31, jq = tid >> 5;   // 8-way j split
    const int p = blockIdx.x * 32 + pl;
    float sc = 0.f;
    #pragma unroll 4
    for (int j = jq; j < 256; j += 8) {
        float v = preT[(size_t)j * N_ANTES + p] + u[j];
        sc = fmaf(fmaxf(v, 0.f), w2s[j], sc);
    }
    red[tid] = sc;
    __syncthreads();
    if (tid < 32) {
        float s = att_b2[0];
        #pragma unroll
        for (int q = 0; q < 8; ++q) s += red[tid + q * 32];
        scores[blockIdx.x * 32 + tid] = s;
    }
}

// ---------------------------------------------------------------------------
// log-softmax + argmax over 2048 scores (single block)
// ---------------------------------------------------------------------------
__global__ __launch_bounds__(256) void k_att2(
    const float* __restrict__ scores, float* __restrict__ out_t,
    int* __restrict__ idx_t)
{
    __shared__ float smax[256];
    __shared__ int   sidx[256];
    __shared__ float ssum[256];
    const int tid = threadIdx.x;

    float sv[8];
    #pragma unroll
    for (int i = 0; i < 8; ++i) sv[i] = scores[tid * 8 + i];

    float lmax = -INFINITY; int lidx = 0;
    #pragma unroll
    for (int i = 0; i < 8; ++i)
        if (sv[i] > lmax) { lmax = sv[i]; lidx = tid * 8 + i; }
    smax[tid] = lmax; sidx[tid] = lidx;
    __syncthreads();
    for (int off = 128; off > 0; off >>= 1) {
        if (tid < off) {
            float ov = smax[tid + off]; int oi = sidx[tid + off];
            if (ov > smax[tid] || (ov == smax[tid] && oi < sidx[tid])) {
                smax[tid] = ov; sidx[tid] = oi;
            }
        }
        __syncthreads();
    }
    const float gmax = smax[0];
    const int gidx = sidx[0];

    float lsum = 0.f;
    #pragma unroll
    for (int i = 0; i < 8; ++i) lsum += __expf(sv[i] - gmax);
    ssum[tid] = lsum;
    __syncthreads();
    for (int off = 128; off > 0; off >>= 1) {
        if (tid < off) ssum[tid] += ssum[tid + off];
        __syncthreads();
    }
    const float lse = gmax + logf(ssum[0]);

    #pragma unroll
    for (int i = 0; i < 8; ++i)
        out_t[tid * 8 + i] = sv[i] - lse;
    if (tid == 0) idx_t[0] = gidx;
}

// ---------------------------------------------------------------------------
extern "C" void kernel_launch(void* const* d_in, const int* in_sizes, int n_in,
                              void* d_out, int out_size, void* d_ws, size_t ws_size,
                              hipStream_t stream)
{
    (void)in_sizes; (void)n_in; (void)out_size; (void)ws_size;
    const float* context = (const float*)d_in[0];
    const float* S       = (const float*)d_in[1];
    const float* enc_w1  = (const float*)d_in[2];
    const float* enc_b1  = (const float*)d_in[3];
    const float* enc_w2  = (const float*)d_in[4];
    const float* enc_b2  = (const float*)d_in[5];
    const float* w_ih    = (const float*)d_in[6];
    const float* w_hh    = (const float*)d_in[7];
    const float* b_ih    = (const float*)d_in[8];
    const float* b_hh    = (const float*)d_in[9];
    const float* att_w1  = (const float*)d_in[10];
    const float* att_b1  = (const float*)d_in[11];
    const float* att_w2  = (const float*)d_in[12];
    const float* att_b2  = (const float*)d_in[13];
    float* out = (float*)d_out;
    float* ws  = (float*)d_ws;

    // ws layout (float offsets)
    float* h      = ws;                        // 1,048,576
    float* c      = ws + 1048576;              // 1,048,576
    float* buf4M  = ws + 2097152;              // hid1, then splitk pA (1,048,576)
    float* preT   = ws + 3145728;              // 524,288
    float* partB  = ws + 3670016;              // splitk pB (1,048,576)
    float* wpkT   = ws + 4718592;              // 262,144 + 4,096 pad
    float* rowsum = ws + 4984832;              // 1,024
    float* e_acc  = ws + 4985856;              // 4,096
    float* scores = ws + 4989952;              // 2,048
    float* WbT    = ws + 4992000;              // 65,536
    int*   idxbuf = (int*)(ws + 5057536);      // 16

    hipMemsetAsync(c, 0, (size_t)N_TRAIN * ENC * sizeof(float), stream);
    hipMemsetAsync(e_acc, 0, (size_t)MAX_LEN * ENC * sizeof(float), stream);

    k_rowsum<<<1024, 256, 0, stream>>>(w_ih, rowsum);
    k_packT<<<1024, 256, 0, stream>>>(w_hh, wpkT);
    k_wbT<<<256, 256, 0, stream>>>(att_w1, WbT);

    // encoder
    float* hid1 = buf4M;
    dim3 g1(N_TRAIN / 64, N_HID / 64);
    gemm_abT<true><<<g1, 256, 0, stream>>>(context, enc_w1, enc_b1, hid1,
                                           N_TRAIN, N_HID, N_FEAT, N_FEAT, N_FEAT, N_HID);
    dim3 g2(N_TRAIN / 64, ENC / 64);
    gemm_abT<false><<<g2, 256, 0, stream>>>(hid1, enc_w2, enc_b2, h,
                                            N_TRAIN, ENC, N_HID, N_HID, N_HID, ENC);
    // preT = Wa @ S (split-K partials; buf4M reused after gemm #2 read hid1)
    dim3 g3(ATT_H / 64, N_ANTES / 64, KSPLIT);
    gemm_ab_splitk<<<g3, 256, 0, stream>>>(att_w1, S, buf4M, partB,
                                           ATT_H, N_ANTES, N_TRAIN,
                                           N_TRAIN + ENC, N_ANTES, N_ANTES);
    k_reduce<<<(ATT_H * N_ANTES) / 256, 256, 0, stream>>>(buf4M, partB, preT);

    for (int t = 0; t < MAX_LEN; ++t) {
        k_lstm<<<N_TRAIN / LROWS, 1024, 0, stream>>>(h, c, wpkT, rowsum, b_ih,
                                                     b_hh, S, idxbuf, t,
                                                     e_acc + t * 256);
        k_att1<<<N_ANTES / 32, 256, 0, stream>>>(preT, e_acc + t * 256, WbT,
                                                 att_b1, att_w2, att_b2, scores);
        k_att2<<<1, 256, 0, stream>>>(scores, out + t * N_ANTES, idxbuf + t);
    }
}